// Round 8
// baseline (2418.275 us; speedup 1.0000x reference)
//
#include <hip/hip_runtime.h>

typedef short short8 __attribute__((ext_vector_type(8)));
typedef float floatx4 __attribute__((ext_vector_type(4)));

__device__ __forceinline__ unsigned short bf16rn(float x) {
  union { float f; unsigned int u; } v; v.f = x;
  unsigned int r = v.u + 0x7fffu + ((v.u >> 16) & 1u);
  return (unsigned short)(r >> 16);
}
__device__ __forceinline__ float bf16f(unsigned short h) {
  union { unsigned int u; float f; } v; v.u = ((unsigned int)h) << 16;
  return v.f;
}
__device__ __forceinline__ void gload16(const void* g, void* l) {
  __builtin_amdgcn_global_load_lds((const __attribute__((address_space(1))) unsigned int*)g,
                                   (__attribute__((address_space(3))) unsigned int*)l, 16, 0, 0);
}
__device__ __forceinline__ unsigned swz128(int row) {
  return ((row & 1) << 6) | ((row & 2) << 4) | ((row & 4) << 2);
}
__device__ __forceinline__ unsigned s4of(int row) {
  return ((row & 1) << 2) | (row & 2) | ((row & 4) >> 2);
}

// ---------------------------------------------------------------------------
// W2 pack: per (kk, cb) a 32KB tile = exact LDS A-image (conv2m format).
// ---------------------------------------------------------------------------
__global__ __launch_bounds__(256) void k_w2p(const float* __restrict__ w2,
                                             unsigned short* __restrict__ w2p) {
  __shared__ float sm[20736];
  const int t = threadIdx.x;
  const int co = blockIdx.x;  // 0..255
  for (int q = t; q < 20736; q += 256) sm[q] = w2[(size_t)co * 20736 + q];
  __syncthreads();
  const unsigned s4 = s4of(co);
  unsigned short* base = w2p + (size_t)co * 64;
  for (int q = t; q < 5184; q += 256) {  // 81 kk x 8 cb x 8 chunks
    int kk = q >> 6, r = q & 63, cb = r >> 3, cp = r & 7;
    unsigned src = (unsigned)cp ^ s4;
    int half = src >> 2, oct = src & 3;
    const float* col = &sm[(cb * 32 + oct * 8) * 81 + kk];
    union { unsigned short u[8]; uint4 v; } pk;
#pragma unroll
    for (int j = 0; j < 8; ++j) {
      float v = col[j * 81];
      unsigned short hi = bf16rn(v);
      pk.u[j] = half ? bf16rn(v - bf16f(hi)) : hi;
    }
    *(uint4*)(base + (size_t)(kk * 8 + cb) * 16384 + cp * 8) = pk.v;
  }
}

// ---------------------------------------------------------------------------
// conv1: NHWC split-bf16 out; grid (bc, 4 co-quarters)
// ---------------------------------------------------------------------------
__global__ __launch_bounds__(256) void k_conv1(const float* __restrict__ x, const float* __restrict__ w1,
                                               const float* __restrict__ b1,
                                               unsigned short* __restrict__ h1h,
                                               unsigned short* __restrict__ h1l, int b0) {
  __shared__ float xs[784];
  __shared__ float wsm[64 * 81];
  const int t = threadIdx.x;
  const int b = b0 + blockIdx.x;
  const int coq = blockIdx.y;
  for (int q = t; q < 784; q += 256) xs[q] = x[(size_t)b * 784 + q];
  for (int q = t; q < 5184; q += 256) wsm[q] = w1[coq * 5184 + q];
  __syncthreads();
  const int col = t & 63, yg = t >> 6;
  const int co = coq * 64 + col;
  const float bv = b1[co];
  unsigned short* oh = h1h + (size_t)blockIdx.x * 102400 + co;
  unsigned short* ol = h1l + (size_t)blockIdx.x * 102400 + co;
  for (int yy = 0; yy < 5; ++yy) {
    const int y = yg * 5 + yy;
    float acc[20];
#pragma unroll
    for (int i = 0; i < 20; ++i) acc[i] = bv;
    for (int ky = 0; ky < 9; ++ky) {
      float row[28];
#pragma unroll
      for (int cc = 0; cc < 28; ++cc) row[cc] = xs[(y + ky) * 28 + cc];
#pragma unroll
      for (int kx = 0; kx < 9; ++kx) {
        float wv = wsm[col * 81 + ky * 9 + kx];
#pragma unroll
        for (int xx = 0; xx < 20; ++xx) acc[xx] += row[xx + kx] * wv;
      }
    }
#pragma unroll
    for (int xx = 0; xx < 20; ++xx) {
      unsigned short hi = bf16rn(acc[xx]);
      unsigned short lo = bf16rn(acc[xx] - bf16f(hi));
      size_t p = (size_t)(y * 20 + xx) * 256;
      oh[p] = hi; ol[p] = lo;
    }
  }
}

// ---------------------------------------------------------------------------
// conv2 GEMM, wave-specialized producer/consumer: 512 threads = 2 groups of
// 4 waves. Group X computes even steps while Y stages the next step, roles
// alternate; ONE barrier/step. Key mechanism: s_waitcnt vmcnt(0) before
// s_barrier is PER-WAVE -- compute waves have 0 outstanding vmem (instant),
// stage waves' drain overlaps the other group's 48-MFMA phase. 80KB LDS
// (2x40KB buffers), 2 blocks/CU = 16 waves/CU. Step body/swizzles identical
// to the proven r0 kernel. Parity-split accumulators -> 8 PART slices
// (9216n x 256co each, r5-proven layout), redsquash per 256-batch half.
// ---------------------------------------------------------------------------
__global__ __launch_bounds__(512, 4) void k_conv2m(const unsigned short* __restrict__ h1h,
                                                   const unsigned short* __restrict__ h1l,
                                                   const unsigned short* __restrict__ w2p,
                                                   float* __restrict__ part) {
  __shared__ __align__(16) char smem[81920];
  const int t = threadIdx.x;
  const int grp = t >> 8;          // 0 = X (computes even s), 1 = Y (odd s)
  const int u = t & 255;           // index within group
  const int lin = blockIdx.x + 144 * blockIdx.z;   // 0..575
  const int xcd = lin & 7, idx = lin >> 3;         // idx 0..71
  const int zz = xcd & 3;                          // kk-range, XCD pair {zz, zz+4}
  const int n0 = ((xcd >> 2) * 72 + idx) * 64;     // n-block (local, 0..9151)
  const int kk0 = (zz == 0) ? 0 : (21 + 20 * (zz - 1));
  const int kkn = (zz == 0) ? 21 : 20;

  const int wid = (t >> 6) & 3, lane = t & 63;
  const int l15 = lane & 15, l4 = lane >> 4;
  const int brow = u >> 2, bc4 = u & 3;
  size_t bsrc;
  {
    int nloc = n0 + brow;
    int bi = nloc / 36, pp = nloc - bi * 36;
    int oy = pp / 6, ox = pp - oy * 6;
    bsrc = ((size_t)((bi * 20 + 2 * oy) * 20 + 2 * ox)) * 256;
  }
  const unsigned bswz = swz128(brow);
  const unsigned bo_hi = (unsigned)(brow * 128) + (((unsigned)(bc4 * 16)) ^ bswz);
  const unsigned bo_lo = (unsigned)(brow * 128) + (((unsigned)(64 + bc4 * 16)) ^ bswz);

  floatx4 acc[4][4];
#pragma unroll
  for (int i = 0; i < 4; ++i)
#pragma unroll
    for (int j = 0; j < 4; ++j) acc[i][j] = (floatx4)0.f;

  const int S = kkn * 8;  // 168 or 160 (even -> balanced parity split)

  auto STAGE = [&](int sidx, char* buf) {
    const int kk = kk0 + (sidx >> 3), cb = sidx & 7;
    const int ky = kk / 9, kx = kk - ky * 9;
    const int koff = (ky * 20 + kx) * 256 + cb * 32;
    const unsigned short* abase = w2p + (size_t)(kk * 8 + cb) * 16384;
#pragma unroll
    for (int j = 0; j < 8; ++j) {
      const int seg = j * 4 + wid;  // 0..31 x 1KB
      gload16(abase + seg * 512 + lane * 8, buf + seg * 1024);
    }
    uint4 vh = *(const uint4*)(h1h + bsrc + koff + bc4 * 8);
    uint4 vl = *(const uint4*)(h1l + bsrc + koff + bc4 * 8);
    *(uint4*)(buf + 32768 + bo_hi) = vh;
    *(uint4*)(buf + 32768 + bo_lo) = vl;
  };

  if (grp == 1) STAGE(0, smem);   // prologue: Y stages step 0 into buf0
  __syncthreads();

  for (int s = 0; s < S; ++s) {
    char* bcur = smem + (s & 1) * 40960;
    if ((s & 1) == grp) {
      // --- compute step s: 16 frag reads, 48 MFMA (r0 body verbatim) ---
      short8 bh[4], blo[4];
#pragma unroll
      for (int nf = 0; nf < 4; ++nf) {
        const int br = nf * 16 + l15;
        const unsigned sw = swz128(br);
        bh[nf]  = *(const short8*)(bcur + 32768 + br * 128 + (((unsigned)(l4 * 16)) ^ sw));
        blo[nf] = *(const short8*)(bcur + 32768 + br * 128 + (((unsigned)(64 + l4 * 16)) ^ sw));
      }
#pragma unroll
      for (int mf = 0; mf < 4; ++mf) {
        const int ar = wid * 64 + mf * 16 + l15;
        const unsigned sw = swz128(ar);
        short8 ah = *(const short8*)(bcur + ar * 128 + (((unsigned)(l4 * 16)) ^ sw));
        short8 al = *(const short8*)(bcur + ar * 128 + (((unsigned)(64 + l4 * 16)) ^ sw));
#pragma unroll
        for (int nf = 0; nf < 4; ++nf) {
          acc[mf][nf] = __builtin_amdgcn_mfma_f32_16x16x32_bf16(ah, bh[nf], acc[mf][nf], 0, 0, 0);
          acc[mf][nf] = __builtin_amdgcn_mfma_f32_16x16x32_bf16(ah, blo[nf], acc[mf][nf], 0, 0, 0);
          acc[mf][nf] = __builtin_amdgcn_mfma_f32_16x16x32_bf16(al, bh[nf], acc[mf][nf], 0, 0, 0);
        }
      }
    } else if (s + 1 < S) {
      STAGE(s + 1, smem + ((s + 1) & 1) * 40960);
    }
    __syncthreads();
  }
  // epilogue: group parity -> slice zz*2+grp; D col(n)=lane&15,
  // row(co)=(lane>>4)*4+reg.
  float* po = part + (size_t)(zz * 2 + grp) * 2359296;
#pragma unroll
  for (int mf = 0; mf < 4; ++mf) {
#pragma unroll
    for (int nf = 0; nf < 4; ++nf) {
      int cog = wid * 64 + mf * 16 + l4 * 4;
      int ng = n0 + nf * 16 + l15;
      *(floatx4*)&po[(size_t)ng * 256 + cog] = acc[mf][nf];
    }
  }
}

// reduce 8 K/parity-split partials + bias, squash -> PRI (per 256-batch
// half; pri pointer pre-offset by caller). grid 1152.
__global__ __launch_bounds__(256) void k_redsquash(const float* __restrict__ part,
                                                   const float* __restrict__ b2,
                                                   float* __restrict__ pri) {
  const int idx = blockIdx.x * 256 + threadIdx.x;  // < 294912
  const int n = idx >> 5, cap = idx & 31;
  const size_t o = (size_t)n * 256 + cap * 8;
  float s[8];
#pragma unroll
  for (int j = 0; j < 8; ++j) s[j] = b2[cap * 8 + j];
#pragma unroll
  for (int z = 0; z < 8; ++z) {
    const float4 a0 = *(const float4*)&part[(size_t)z * 2359296 + o];
    const float4 a1 = *(const float4*)&part[(size_t)z * 2359296 + o + 4];
    s[0] += a0.x; s[1] += a0.y; s[2] += a0.z; s[3] += a0.w;
    s[4] += a1.x; s[5] += a1.y; s[6] += a1.z; s[7] += a1.w;
  }
  float ss = 0.f;
#pragma unroll
  for (int j = 0; j < 8; ++j) ss += s[j] * s[j];
  float nn = sqrtf(ss);
  float sc = ss / (1.f + ss) / (nn + 1e-8f);
  float4 o0, o1;
  o0.x = s[0] * sc; o0.y = s[1] * sc; o0.z = s[2] * sc; o0.w = s[3] * sc;
  o1.x = s[4] * sc; o1.y = s[5] * sc; o1.z = s[6] * sc; o1.w = s[7] * sc;
  *(float4*)&pri[o] = o0;
  *(float4*)&pri[o + 4] = o1;
}

// ---------------------------------------------------------------------------
// routing (r6 proven). rw_s [d(16)][il*8+k] pad 516; p_s [bl(16)][off].
// float4-vectorized staging; compute identical to proven scalar version.
// ---------------------------------------------------------------------------
__global__ __launch_bounds__(256, 2) void k_passA(const float* __restrict__ rw, const float* __restrict__ pri,
                                                  const float* __restrict__ cbuf, float* __restrict__ spart,
                                                  int iter) {
  __shared__ __align__(16) float rw_s[16 * 516];
  __shared__ __align__(16) float p_s[16 * 516];
  __shared__ __align__(16) float c_s[1024];
  const int t = threadIdx.x;
  const int b0 = blockIdx.x * 16, i0 = blockIdx.y * 64, o = blockIdx.z;
  const float* rsrc = rw + (size_t)o * 147456 + (size_t)i0 * 128;
  for (int m = t; m < 2048; m += 256) {
    int il = m >> 5, r = m & 31, d = r >> 1, kh = (m & 1) * 4;
    float4 v = *(const float4*)&rsrc[il * 128 + d * 8 + kh];
    *(float4*)&rw_s[d * 516 + il * 8 + kh] = v;
  }
  for (int m = t; m < 2048; m += 256) {
    int bl = m >> 7, off = (m & 127) * 4;
    float4 v = *(const float4*)&pri[(size_t)(b0 + bl) * 9216 + i0 * 8 + off];
    *(float4*)&p_s[bl * 516 + off] = v;
  }
  if (iter > 0) {
    for (int m = t; m < 256; m += 256) {
      int bl = m >> 4, il4 = (m & 15) * 4;
      float4 v = *(const float4*)&cbuf[(size_t)((b0 + bl) * 10 + o) * 1152 + i0 + il4];
      *(float4*)&c_s[bl * 64 + il4] = v;
    }
  }
  __syncthreads();
  const int d = t & 15, bl = t >> 4;
  float acc = 0.f;
  for (int il = 0; il < 64; ++il) {
    float cv = (iter == 0) ? 0.1f : c_s[bl * 64 + il];
    float4 p0 = *(float4*)&p_s[bl * 516 + il * 8];
    float4 p1 = *(float4*)&p_s[bl * 516 + il * 8 + 4];
    float4 r0 = *(float4*)&rw_s[d * 516 + il * 8];
    float4 r1 = *(float4*)&rw_s[d * 516 + il * 8 + 4];
    float dt = r0.x * p0.x + r0.y * p0.y + r0.z * p0.z + r0.w * p0.w +
               r1.x * p1.x + r1.y * p1.y + r1.z * p1.z + r1.w * p1.w;
    acc += cv * dt;
  }
  spart[((size_t)blockIdx.y * 512 + (b0 + bl)) * 160 + o * 16 + d] = acc;
}

__global__ __launch_bounds__(256) void k_reduce(const float* __restrict__ spart, float* __restrict__ outc,
                                                float* __restrict__ len_out, int final_) {
  const int t = threadIdx.x;
  const int b = blockIdx.x;
  if (t >= 160) return;
  const int o = t / 16, d = t & 15;
  float s = 0.f;
  for (int ic = 0; ic < 18; ++ic) s += spart[((size_t)ic * 512 + b) * 160 + t];
  float ss = s * s;
  ss += __shfl_xor(ss, 1, 16);
  ss += __shfl_xor(ss, 2, 16);
  ss += __shfl_xor(ss, 4, 16);
  ss += __shfl_xor(ss, 8, 16);
  float n = sqrtf(ss);
  float sc = ss / (1.f + ss) / (n + 1e-8f);
  outc[(size_t)b * 160 + t] = sc * s;
  if (final_ && d == 0) len_out[b * 10 + o] = sc * n;
}

__global__ __launch_bounds__(256, 2) void k_passB(const float* __restrict__ rw, const float* __restrict__ pri,
                                                  const float* __restrict__ outc, float* __restrict__ blog,
                                                  int accum) {
  __shared__ __align__(16) float rw_s[16 * 516];
  __shared__ __align__(16) float p_s[16 * 516];
  __shared__ float oc_s[256];
  const int t = threadIdx.x;
  const int b0 = blockIdx.x * 16, i0 = blockIdx.y * 64, o = blockIdx.z;
  const float* rsrc = rw + (size_t)o * 147456 + (size_t)i0 * 128;
  for (int m = t; m < 2048; m += 256) {
    int il = m >> 5, r = m & 31, d = r >> 1, kh = (m & 1) * 4;
    float4 v = *(const float4*)&rsrc[il * 128 + d * 8 + kh];
    *(float4*)&rw_s[d * 516 + il * 8 + kh] = v;
  }
  for (int m = t; m < 2048; m += 256) {
    int bl = m >> 7, off = (m & 127) * 4;
    float4 v = *(const float4*)&pri[(size_t)(b0 + bl) * 9216 + i0 * 8 + off];
    *(float4*)&p_s[bl * 516 + off] = v;
  }
  oc_s[t] = outc[(size_t)(b0 + (t >> 4)) * 160 + o * 16 + (t & 15)];
  __syncthreads();
  const int il0 = t & 15, bl = t >> 4;
  float ocv[16];
#pragma unroll
  for (int k = 0; k < 16; ++k) ocv[k] = oc_s[bl * 16 + k];
#pragma unroll
  for (int is = 0; is < 4; ++is) {
    const int il = is * 16 + il0;
    float4 p0 = *(float4*)&p_s[bl * 516 + il * 8];
    float4 p1 = *(float4*)&p_s[bl * 516 + il * 8 + 4];
    float acc = 0.f;
#pragma unroll
    for (int dd = 0; dd < 16; ++dd) {
      float4 r0 = *(float4*)&rw_s[dd * 516 + il * 8];
      float4 r1 = *(float4*)&rw_s[dd * 516 + il * 8 + 4];
      float h = r0.x * p0.x + r0.y * p0.y + r0.z * p0.z + r0.w * p0.w +
                r1.x * p1.x + r1.y * p1.y + r1.z * p1.z + r1.w * p1.w;
      acc += h * ocv[dd];
    }
    size_t gi = (size_t)((b0 + bl) * 10 + o) * 1152 + i0 + il;
    blog[gi] = accum ? (blog[gi] + acc) : acc;
  }
}

__global__ __launch_bounds__(256) void k_softmax(const float* __restrict__ blog, float* __restrict__ cbuf) {
  const int b = blockIdx.x;
  const int i = blockIdx.y * 256 + threadIdx.x;
  if (i >= 1152) return;
  float v[10];
  float m = -1e30f;
#pragma unroll
  for (int o = 0; o < 10; ++o) {
    v[o] = blog[(size_t)(b * 10 + o) * 1152 + i];
    m = fmaxf(m, v[o]);
  }
  float s = 0.f;
#pragma unroll
  for (int o = 0; o < 10; ++o) {
    v[o] = __expf(v[o] - m);
    s += v[o];
  }
  float inv = 1.f / s;
#pragma unroll
  for (int o = 0; o < 10; ++o) cbuf[(size_t)(b * 10 + o) * 1152 + i] = v[o] * inv;
}

__global__ __launch_bounds__(256) void k_argmax(const float* __restrict__ len_, const float* __restrict__ outc,
                                                int* __restrict__ win, float* __restrict__ oc16) {
  const int b = blockIdx.x * 256 + threadIdx.x;
  if (b >= 512) return;
  float best = len_[b * 10];
  int wi = 0;
  for (int o = 1; o < 10; ++o) {
    float v = len_[b * 10 + o];
    if (v > best) { best = v; wi = o; }
  }
  win[b] = wi;
  for (int k = 0; k < 16; ++k) oc16[b * 16 + k] = outc[(size_t)b * 160 + wi * 16 + k];
}

__global__ __launch_bounds__(256) void k_dec1(const float* __restrict__ oc16, const int* __restrict__ win,
                                              const float* __restrict__ w, const float* __restrict__ bias,
                                              float* __restrict__ d1) {
  const int b = blockIdx.x, t = threadIdx.x;
  const int wi = win[b];
  float ocv[16];
#pragma unroll
  for (int k = 0; k < 16; ++k) ocv[k] = oc16[b * 16 + k];
#pragma unroll
  for (int rep = 0; rep < 2; ++rep) {
    int j = t + rep * 256;
    const float* wr = w + (size_t)j * 160 + wi * 16;
    float acc = bias[j];
#pragma unroll
    for (int k = 0; k < 16; ++k) acc += ocv[k] * wr[k];
    d1[(size_t)b * 512 + j] = fmaxf(acc, 0.f);
  }
}

template <int K, int ACT>
__global__ __launch_bounds__(256) void k_fc(const float* __restrict__ in, const float* __restrict__ w,
                                            const float* __restrict__ bias, float* __restrict__ out, int M) {
  __shared__ __align__(16) float w_s[16 * 64];
  __shared__ __align__(16) float i_s[16 * 64];
  const int t = threadIdx.x;
  const int j0 = blockIdx.x * 64, b0 = blockIdx.y * 64;
  const int tx = t & 15, ty = t >> 4;
  const int jl = tx * 4, bl = ty * 4;
  float acc[4][4];
#pragma unroll
  for (int i = 0; i < 4; ++i)
#pragma unroll
    for (int j = 0; j < 4; ++j) acc[i][j] = 0.f;
  const int rr = t >> 2, kq = (t & 3) * 4;
  for (int k0 = 0; k0 < K; k0 += 16) {
    __syncthreads();
    float4 wv = make_float4(0.f, 0.f, 0.f, 0.f);
    if (j0 + rr < M) wv = *(const float4*)&w[(size_t)(j0 + rr) * K + k0 + kq];
    float4 iv = *(const float4*)&in[(size_t)(b0 + rr) * K + k0 + kq];
    w_s[(kq + 0) * 64 + rr] = wv.x;
    w_s[(kq + 1) * 64 + rr] = wv.y;
    w_s[(kq + 2) * 64 + rr] = wv.z;
    w_s[(kq + 3) * 64 + rr] = wv.w;
    i_s[(kq + 0) * 64 + rr] = iv.x;
    i_s[(kq + 1) * 64 + rr] = iv.y;
    i_s[(kq + 2) * 64 + rr] = iv.z;
    i_s[(kq + 3) * 64 + rr] = iv.w;
    __syncthreads();
#pragma unroll
    for (int k = 0; k < 16; ++k) {
      float4 a = *(float4*)&w_s[k * 64 + jl];
      float4 v = *(float4*)&i_s[k * 64 + bl];
      float av[4] = {a.x, a.y, a.z, a.w};
      float vv[4] = {v.x, v.y, v.z, v.w};
#pragma unroll
      for (int jj = 0; jj < 4; ++jj)
#pragma unroll
        for (int bb = 0; bb < 4; ++bb) acc[jj][bb] += av[jj] * vv[bb];
    }
  }
#pragma unroll
  for (int jj = 0; jj < 4; ++jj) {
    int j = j0 + jl + jj;
    if (j >= M) continue;
    float bs = bias[j];
#pragma unroll
    for (int bb = 0; bb < 4; ++bb) {
      float v = acc[jj][bb] + bs;
      if (ACT == 0) {
        v = fmaxf(v, 0.f);
      } else {
        v = 1.f / (1.f + __expf(-v));
        v = fminf(fmaxf(v, 0.f), 1.f);
      }
      out[(size_t)(b0 + bl + bb) * M + j] = v;
    }
  }
}

extern "C" void kernel_launch(void* const* d_in, const int* in_sizes, int n_in,
                              void* d_out, int out_size, void* d_ws, size_t ws_size,
                              hipStream_t stream) {
  (void)in_sizes; (void)n_in; (void)out_size; (void)ws_size;
  const float* x   = (const float*)d_in[0];
  const float* w1  = (const float*)d_in[1];
  const float* b1  = (const float*)d_in[2];
  const float* w2  = (const float*)d_in[3];
  const float* b2  = (const float*)d_in[4];
  const float* rw  = (const float*)d_in[5];
  const float* d1w = (const float*)d_in[6];
  const float* d1b = (const float*)d_in[7];
  const float* d2w = (const float*)d_in[8];
  const float* d2b = (const float*)d_in[9];
  const float* d3w = (const float*)d_in[10];
  const float* d3b = (const float*)d_in[11];
  float* out = (float*)d_out;

  char* wsb = (char*)d_ws;
  size_t cur = 0;
  auto alloc = [&](size_t bytes) -> char* {
    char* p = wsb + cur;
    cur += (bytes + 255) & ~(size_t)255;
    return p;
  };
  unsigned short* W2P = (unsigned short*)alloc(21233664);  // 648 x 32KB tiles
  float* PART = (float*)alloc(75497472);                   // 8 x 9216 x 256 f32
  float* PRI  = (float*)alloc(18874368);                   // 18432 x 256
  float* OUTC = (float*)alloc(327680);                     // 512 x 160
  float* OC   = (float*)alloc(32768);
  int*   WIN  = (int*)alloc(2048);
  float* D1   = (float*)alloc(1048576);
  float* D2   = (float*)alloc(2097152);
  unsigned short* H1H = (unsigned short*)alloc(52428800);  // 256b x 400 x 256
  unsigned short* H1L = (unsigned short*)alloc(52428800);
  // routing-phase overlays in the dead H1 region (53.1 MB < 104.9 MB):
  float* C  = (float*)H1H;                                 // 23.6 MB
  float* BL = (float*)((char*)H1H + 23592960);             // 23.6 MB
  float* SP = (float*)((char*)H1H + 47185920);             // 5.9 MB

  k_w2p<<<256, 256, 0, stream>>>(w2, W2P);
  for (int b0 = 0; b0 < 512; b0 += 256) {
    k_conv1<<<dim3(256, 4), 256, 0, stream>>>(x, w1, b1, H1H, H1L, b0);
    k_conv2m<<<dim3(144, 1, 4), 512, 0, stream>>>(H1H, H1L, W2P, PART);
    k_redsquash<<<1152, 256, 0, stream>>>(PART, b2, PRI + (size_t)b0 * 36 * 256);
  }

  dim3 gAB(32, 18, 10);
  k_passA<<<gAB, 256, 0, stream>>>(rw, PRI, C, SP, 0);
  k_reduce<<<512, 256, 0, stream>>>(SP, OUTC, out, 0);
  k_passB<<<gAB, 256, 0, stream>>>(rw, PRI, OUTC, BL, 0);
  k_softmax<<<dim3(512, 5), 256, 0, stream>>>(BL, C);
  k_passA<<<gAB, 256, 0, stream>>>(rw, PRI, C, SP, 1);
  k_reduce<<<512, 256, 0, stream>>>(SP, OUTC, out, 0);
  k_passB<<<gAB, 256, 0, stream>>>(rw, PRI, OUTC, BL, 1);
  k_softmax<<<dim3(512, 5), 256, 0, stream>>>(BL, C);
  k_passA<<<gAB, 256, 0, stream>>>(rw, PRI, C, SP, 2);
  k_reduce<<<512, 256, 0, stream>>>(SP, OUTC, out, 1);

  k_argmax<<<2, 256, 0, stream>>>(out, OUTC, WIN, OC);
  k_dec1<<<512, 256, 0, stream>>>(OC, WIN, d1w, d1b, D1);
  k_fc<512, 0><<<dim3(16, 8), 256, 0, stream>>>(D1, d2w, d2b, D2, 1024);
  k_fc<1024, 1><<<dim3(13, 8), 256, 0, stream>>>(D2, d3w, d3b, out + 5120, 784);
}

// Round 9
// 1533.616 us; speedup vs baseline: 1.5768x; 1.5768x over previous
//
#include <hip/hip_runtime.h>

typedef short short8 __attribute__((ext_vector_type(8)));
typedef float floatx4 __attribute__((ext_vector_type(4)));

__device__ __forceinline__ unsigned short bf16rn(float x) {
  union { float f; unsigned int u; } v; v.f = x;
  unsigned int r = v.u + 0x7fffu + ((v.u >> 16) & 1u);
  return (unsigned short)(r >> 16);
}
__device__ __forceinline__ float bf16f(unsigned short h) {
  union { unsigned int u; float f; } v; v.u = ((unsigned int)h) << 16;
  return v.f;
}
__device__ __forceinline__ void gload16(const void* g, void* l) {
  __builtin_amdgcn_global_load_lds((const __attribute__((address_space(1))) unsigned int*)g,
                                   (__attribute__((address_space(3))) unsigned int*)l, 16, 0, 0);
}
__device__ __forceinline__ unsigned swz128(int row) {
  return ((row & 1) << 6) | ((row & 2) << 4) | ((row & 4) << 2);
}
__device__ __forceinline__ unsigned s4of(int row) {
  return ((row & 1) << 2) | (row & 2) | ((row & 4) >> 2);
}

// ---------------------------------------------------------------------------
// W2 pack: per (kk, cb) a 32KB tile = exact LDS A-image (conv2m format).
// ---------------------------------------------------------------------------
__global__ __launch_bounds__(256) void k_w2p(const float* __restrict__ w2,
                                             unsigned short* __restrict__ w2p) {
  __shared__ float sm[20736];
  const int t = threadIdx.x;
  const int co = blockIdx.x;  // 0..255
  for (int q = t; q < 20736; q += 256) sm[q] = w2[(size_t)co * 20736 + q];
  __syncthreads();
  const unsigned s4 = s4of(co);
  unsigned short* base = w2p + (size_t)co * 64;
  for (int q = t; q < 5184; q += 256) {  // 81 kk x 8 cb x 8 chunks
    int kk = q >> 6, r = q & 63, cb = r >> 3, cp = r & 7;
    unsigned src = (unsigned)cp ^ s4;
    int half = src >> 2, oct = src & 3;
    const float* col = &sm[(cb * 32 + oct * 8) * 81 + kk];
    union { unsigned short u[8]; uint4 v; } pk;
#pragma unroll
    for (int j = 0; j < 8; ++j) {
      float v = col[j * 81];
      unsigned short hi = bf16rn(v);
      pk.u[j] = half ? bf16rn(v - bf16f(hi)) : hi;
    }
    *(uint4*)(base + (size_t)(kk * 8 + cb) * 16384 + cp * 8) = pk.v;
  }
}

// ---------------------------------------------------------------------------
// conv1: NHWC split-bf16 out; grid (bc, 4 co-quarters)
// ---------------------------------------------------------------------------
__global__ __launch_bounds__(256) void k_conv1(const float* __restrict__ x, const float* __restrict__ w1,
                                               const float* __restrict__ b1,
                                               unsigned short* __restrict__ h1h,
                                               unsigned short* __restrict__ h1l, int b0) {
  __shared__ float xs[784];
  __shared__ float wsm[64 * 81];
  const int t = threadIdx.x;
  const int b = b0 + blockIdx.x;
  const int coq = blockIdx.y;
  for (int q = t; q < 784; q += 256) xs[q] = x[(size_t)b * 784 + q];
  for (int q = t; q < 5184; q += 256) wsm[q] = w1[coq * 5184 + q];
  __syncthreads();
  const int col = t & 63, yg = t >> 6;
  const int co = coq * 64 + col;
  const float bv = b1[co];
  unsigned short* oh = h1h + (size_t)blockIdx.x * 102400 + co;
  unsigned short* ol = h1l + (size_t)blockIdx.x * 102400 + co;
  for (int yy = 0; yy < 5; ++yy) {
    const int y = yg * 5 + yy;
    float acc[20];
#pragma unroll
    for (int i = 0; i < 20; ++i) acc[i] = bv;
    for (int ky = 0; ky < 9; ++ky) {
      float row[28];
#pragma unroll
      for (int cc = 0; cc < 28; ++cc) row[cc] = xs[(y + ky) * 28 + cc];
#pragma unroll
      for (int kx = 0; kx < 9; ++kx) {
        float wv = wsm[col * 81 + ky * 9 + kx];
#pragma unroll
        for (int xx = 0; xx < 20; ++xx) acc[xx] += row[xx + kx] * wv;
      }
    }
#pragma unroll
    for (int xx = 0; xx < 20; ++xx) {
      unsigned short hi = bf16rn(acc[xx]);
      unsigned short lo = bf16rn(acc[xx] - bf16f(hi));
      size_t p = (size_t)(y * 20 + xx) * 256;
      oh[p] = hi; ol[p] = lo;
    }
  }
}

// ---------------------------------------------------------------------------
// conv2 GEMM: r0/r6 proven (353us/dispatch). BM=256 x BN=64, BK=32, z=4.
// ---------------------------------------------------------------------------
__global__ __launch_bounds__(256) void k_conv2m(const unsigned short* __restrict__ h1h,
                                                const unsigned short* __restrict__ h1l,
                                                const unsigned short* __restrict__ w2p,
                                                float* __restrict__ part, int b0) {
  __shared__ __align__(16) char smem[40960];
  const int t = threadIdx.x;
  const int lin = blockIdx.x + 144 * blockIdx.z;   // 0..575
  const int xcd = lin & 7, idx = lin >> 3;         // idx 0..71
  const int zz = xcd & 3;                          // kk-range, XCD pair {zz, zz+4}
  const int n0 = ((xcd >> 2) * 72 + idx) * 64;     // n-block
  const int kk0 = (zz == 0) ? 0 : (21 + 20 * (zz - 1));
  const int kkn = (zz == 0) ? 21 : 20;

  const int wid = t >> 6, lane = t & 63;
  const int l15 = lane & 15, l4 = lane >> 4;
  const int brow = t >> 2, bc4 = t & 3;
  size_t bsrc;
  {
    int nloc = n0 + brow;
    int bi = nloc / 36, pp = nloc - bi * 36;
    int oy = pp / 6, ox = pp - oy * 6;
    bsrc = ((size_t)((bi * 20 + 2 * oy) * 20 + 2 * ox)) * 256;
  }
  const unsigned bswz = swz128(brow);
  const unsigned bo_hi = (unsigned)(brow * 128) + (((unsigned)(bc4 * 16)) ^ bswz);
  const unsigned bo_lo = (unsigned)(brow * 128) + (((unsigned)(64 + bc4 * 16)) ^ bswz);

  floatx4 acc[4][4];
#pragma unroll
  for (int i = 0; i < 4; ++i)
#pragma unroll
    for (int j = 0; j < 4; ++j) acc[i][j] = (floatx4)0.f;

  for (int kq = 0; kq < kkn; ++kq) {
    const int kk = kk0 + kq;
    const int ky = kk / 9, kx = kk - ky * 9;
    const int koff = (ky * 20 + kx) * 256;
    for (int cb = 0; cb < 8; ++cb) {
      const unsigned short* abase = w2p + (size_t)(kk * 8 + cb) * 16384;
#pragma unroll
      for (int j = 0; j < 8; ++j) {
        const int seg = j * 4 + wid;
        gload16(abase + seg * 512 + lane * 8, smem + seg * 1024);
      }
      {
        const unsigned short* sh = h1h + bsrc + koff + cb * 32 + bc4 * 8;
        const unsigned short* sl = h1l + bsrc + koff + cb * 32 + bc4 * 8;
        uint4 vh = *(const uint4*)sh;
        uint4 vl = *(const uint4*)sl;
        *(uint4*)(smem + 32768 + bo_hi) = vh;
        *(uint4*)(smem + 32768 + bo_lo) = vl;
      }
      __syncthreads();
      short8 bh[4], blo[4];
#pragma unroll
      for (int nf = 0; nf < 4; ++nf) {
        const int br = nf * 16 + l15;
        const unsigned s = swz128(br);
        bh[nf] = *(const short8*)(smem + 32768 + br * 128 + (((unsigned)(l4 * 16)) ^ s));
        blo[nf] = *(const short8*)(smem + 32768 + br * 128 + (((unsigned)(64 + l4 * 16)) ^ s));
      }
#pragma unroll
      for (int mf = 0; mf < 4; ++mf) {
        const int ar = wid * 64 + mf * 16 + l15;
        const unsigned s = swz128(ar);
        short8 ah = *(const short8*)(smem + ar * 128 + (((unsigned)(l4 * 16)) ^ s));
        short8 al = *(const short8*)(smem + ar * 128 + (((unsigned)(64 + l4 * 16)) ^ s));
#pragma unroll
        for (int nf = 0; nf < 4; ++nf) {
          acc[mf][nf] = __builtin_amdgcn_mfma_f32_16x16x32_bf16(ah, bh[nf], acc[mf][nf], 0, 0, 0);
          acc[mf][nf] = __builtin_amdgcn_mfma_f32_16x16x32_bf16(ah, blo[nf], acc[mf][nf], 0, 0, 0);
          acc[mf][nf] = __builtin_amdgcn_mfma_f32_16x16x32_bf16(al, bh[nf], acc[mf][nf], 0, 0, 0);
        }
      }
      __syncthreads();
    }
  }
  float* po = part + (size_t)zz * 4718592;
#pragma unroll
  for (int mf = 0; mf < 4; ++mf) {
#pragma unroll
    for (int nf = 0; nf < 4; ++nf) {
      int cog = wid * 64 + mf * 16 + l4 * 4;
      int ng = b0 * 36 + n0 + nf * 16 + l15;
      *(floatx4*)&po[(size_t)ng * 256 + cog] = acc[mf][nf];
    }
  }
}

// reduce 4 K-split partials + bias, squash -> PRI
__global__ __launch_bounds__(256) void k_redsquash(const float* __restrict__ part,
                                                   const float* __restrict__ b2,
                                                   float* __restrict__ pri) {
  const int idx = blockIdx.x * 256 + threadIdx.x;  // < 589824
  const int n = idx >> 5, cap = idx & 31;
  const size_t o = (size_t)n * 256 + cap * 8;
  float s[8];
#pragma unroll
  for (int j = 0; j < 8; ++j) s[j] = b2[cap * 8 + j];
#pragma unroll
  for (int z = 0; z < 4; ++z) {
    const float4 a0 = *(const float4*)&part[(size_t)z * 4718592 + o];
    const float4 a1 = *(const float4*)&part[(size_t)z * 4718592 + o + 4];
    s[0] += a0.x; s[1] += a0.y; s[2] += a0.z; s[3] += a0.w;
    s[4] += a1.x; s[5] += a1.y; s[6] += a1.z; s[7] += a1.w;
  }
  float ss = 0.f;
#pragma unroll
  for (int j = 0; j < 8; ++j) ss += s[j] * s[j];
  float nn = sqrtf(ss);
  float sc = ss / (1.f + ss) / (nn + 1e-8f);
  float4 o0, o1;
  o0.x = s[0] * sc; o0.y = s[1] * sc; o0.z = s[2] * sc; o0.w = s[3] * sc;
  o1.x = s[4] * sc; o1.y = s[5] * sc; o1.z = s[6] * sc; o1.w = s[7] * sc;
  *(float4*)&pri[o] = o0;
  *(float4*)&pri[o + 4] = o1;
}

// ---------------------------------------------------------------------------
// RW pack for MFMA passA (r7 verified): per (o, ichunk) a 32KB A-image tile.
// Row r = c32*16 + kobj; chunk c covers m = c32*32 + (c&3)*8 + e ->
// il = c32*4 + (c&3), d = e; hi chunks 0-3 / lo 4-7, pre-swizzled.
// ---------------------------------------------------------------------------
__global__ __launch_bounds__(256) void k_rwp(const float* __restrict__ rw,
                                             unsigned short* __restrict__ rwpa) {
  __shared__ float sm[8192];
  const int t = threadIdx.x;
  const float* src = rw + (size_t)blockIdx.x * 8192;
  for (int q = t; q < 8192; q += 256) sm[q] = src[q];
  __syncthreads();
  const int r = t;                    // row 0..255
  const int c32 = r >> 4, kobj = r & 15;
  const unsigned s4 = s4of(r);
  unsigned short* base = rwpa + (size_t)blockIdx.x * 16384 + r * 64;
#pragma unroll
  for (int cp = 0; cp < 8; ++cp) {
    unsigned c = (unsigned)cp ^ s4;
    int half = c >> 2;
    int il = c32 * 4 + (c & 3);
    const float* col = &sm[il * 128 + kobj * 8];
    union { unsigned short u[8]; uint4 v; } pk;
#pragma unroll
    for (int e = 0; e < 8; ++e) {
      float v = col[e];
      unsigned short hi = bf16rn(v);
      pk.u[e] = half ? bf16rn(v - bf16f(hi)) : hi;
    }
    *(uint4*)(base + cp * 8) = pk.v;
  }
}

// ---------------------------------------------------------------------------
// Fused passA + reduce + squash: block = (16 b) x (1 o) x ALL 18 i-chunks.
// Grid (32, 10) = 320 blocks. Per step (r0's proven 2-barrier structure):
// stage A (32KB rw-tile gload16) + build q = c*p in-reg (r7-verified
// q-build, split-bf16, bank-rotated swizzled ds_write) -> barrier ->
// 16 K-chunks x 3 MFMA across 4 waves, acc persistent in VGPRs -> barrier.
// Epilogue: 4-wave LDS partial sum + shfl squash -> outc (+len on final).
// Eliminates k_reduce and 17/18 of per-block launch/stage latency vs r7.
// ---------------------------------------------------------------------------
__global__ __launch_bounds__(256, 2) void k_passAf(const unsigned short* __restrict__ rwpa,
                                                   const float* __restrict__ pri,
                                                   const float* __restrict__ cbuf,
                                                   float* __restrict__ outc,
                                                   float* __restrict__ len_out,
                                                   int iter, int final_) {
  __shared__ __align__(16) char smem[65536];
  const int t = threadIdx.x;
  const int b0 = blockIdx.x * 16, o = blockIdx.y;
  const int wid = t >> 6, lane = t & 63;
  const int l15 = lane & 15, l4 = lane >> 4;
  const int bl = t >> 4, c32 = t & 15;

  floatx4 acc = (floatx4)0.f;
  for (int ic = 0; ic < 18; ++ic) {
    const int i0 = ic * 64;
    // --- stage A: linear 32KB DMA of packed rw tile ---
    {
      const unsigned short* abase = rwpa + (size_t)(o * 18 + ic) * 16384;
#pragma unroll
      for (int j = 0; j < 8; ++j) {
        const int seg = j * 4 + wid;
        gload16(abase + seg * 512 + lane * 8, smem + seg * 1024);
      }
    }
    // --- q build: thread (bl, c32) covers 32 m values (r7 verified) ---
    {
      const float* psrc = pri + (size_t)(b0 + bl) * 9216 + i0 * 8 + c32 * 32;
      float pv[32];
#pragma unroll
      for (int j = 0; j < 8; ++j) {
        float4 v = *(const float4*)&psrc[j * 4];
        pv[j * 4 + 0] = v.x; pv[j * 4 + 1] = v.y; pv[j * 4 + 2] = v.z; pv[j * 4 + 3] = v.w;
      }
      float cv[4];
      if (iter == 0) {
        cv[0] = cv[1] = cv[2] = cv[3] = 0.1f;
      } else {
        float4 cc = *(const float4*)&cbuf[(size_t)((b0 + bl) * 10 + o) * 1152 + i0 + c32 * 4];
        cv[0] = cc.x; cv[1] = cc.y; cv[2] = cc.z; cv[3] = cc.w;
      }
      union { unsigned short u[32]; uint4 v[4]; } qh, ql;
#pragma unroll
      for (int m = 0; m < 32; ++m) {
        float q = cv[m >> 3] * pv[m];
        unsigned short hi = bf16rn(q);
        qh.u[m] = hi;
        ql.u[m] = bf16rn(q - bf16f(hi));
      }
      const int r = c32 * 16 + bl;
      const unsigned swz = swz128(r);
      char* qbase = smem + 32768 + r * 128;
#pragma unroll
      for (int j = 0; j < 8; ++j) {
        int c = (j + c32) & 7;  // bank-rotated issue order
        uint4 v = (c < 4) ? qh.v[c & 3] : ql.v[c & 3];
        *(uint4*)(qbase + (((unsigned)(c * 16)) ^ swz)) = v;
      }
    }
    __syncthreads();
    // --- MFMA: wave w handles K-chunks w*4 .. w*4+3 ---
#pragma unroll
    for (int cc = 0; cc < 4; ++cc) {
      const int kc = wid * 4 + cc;
      const int rr = kc * 16 + l15;
      const unsigned s = swz128(rr);
      short8 ah  = *(const short8*)(smem + rr * 128 + (((unsigned)(l4 * 16)) ^ s));
      short8 al  = *(const short8*)(smem + rr * 128 + (((unsigned)(64 + l4 * 16)) ^ s));
      short8 bh  = *(const short8*)(smem + 32768 + rr * 128 + (((unsigned)(l4 * 16)) ^ s));
      short8 blo = *(const short8*)(smem + 32768 + rr * 128 + (((unsigned)(64 + l4 * 16)) ^ s));
      acc = __builtin_amdgcn_mfma_f32_16x16x32_bf16(ah, bh, acc, 0, 0, 0);
      acc = __builtin_amdgcn_mfma_f32_16x16x32_bf16(ah, blo, acc, 0, 0, 0);
      acc = __builtin_amdgcn_mfma_f32_16x16x32_bf16(al, bh, acc, 0, 0, 0);
    }
    __syncthreads();
  }
  // --- epilogue: partials [w][bl*16 + kobj], sum, squash, write ---
  *(floatx4*)(smem + wid * 1024 + (l15 * 16 + l4 * 4) * 4) = acc;
  __syncthreads();
  const float* pp = (const float*)smem;
  float s = pp[bl * 16 + c32] + pp[256 + bl * 16 + c32] +
            pp[512 + bl * 16 + c32] + pp[768 + bl * 16 + c32];
  float ss = s * s;
  ss += __shfl_xor(ss, 1, 16);
  ss += __shfl_xor(ss, 2, 16);
  ss += __shfl_xor(ss, 4, 16);
  ss += __shfl_xor(ss, 8, 16);
  float n = sqrtf(ss);
  float sc = ss / (1.f + ss) / (n + 1e-8f);
  outc[(size_t)(b0 + bl) * 160 + o * 16 + c32] = sc * s;
  if (final_ && c32 == 0) len_out[(b0 + bl) * 10 + o] = sc * n;
}

// ---------------------------------------------------------------------------
// passB (r6 proven, scalar). rw_s [d(16)][il*8+k] pad 516.
// ---------------------------------------------------------------------------
__global__ __launch_bounds__(256, 2) void k_passB(const float* __restrict__ rw, const float* __restrict__ pri,
                                                  const float* __restrict__ outc, float* __restrict__ blog,
                                                  int accum) {
  __shared__ __align__(16) float rw_s[16 * 516];
  __shared__ __align__(16) float p_s[16 * 516];
  __shared__ float oc_s[256];
  const int t = threadIdx.x;
  const int b0 = blockIdx.x * 16, i0 = blockIdx.y * 64, o = blockIdx.z;
  const float* rsrc = rw + (size_t)o * 147456 + (size_t)i0 * 128;
  for (int m = t; m < 2048; m += 256) {
    int il = m >> 5, r = m & 31, d = r >> 1, kh = (m & 1) * 4;
    float4 v = *(const float4*)&rsrc[il * 128 + d * 8 + kh];
    *(float4*)&rw_s[d * 516 + il * 8 + kh] = v;
  }
  for (int m = t; m < 2048; m += 256) {
    int bl = m >> 7, off = (m & 127) * 4;
    float4 v = *(const float4*)&pri[(size_t)(b0 + bl) * 9216 + i0 * 8 + off];
    *(float4*)&p_s[bl * 516 + off] = v;
  }
  oc_s[t] = outc[(size_t)(b0 + (t >> 4)) * 160 + o * 16 + (t & 15)];
  __syncthreads();
  const int il0 = t & 15, bl = t >> 4;
  float ocv[16];
#pragma unroll
  for (int k = 0; k < 16; ++k) ocv[k] = oc_s[bl * 16 + k];
#pragma unroll
  for (int is = 0; is < 4; ++is) {
    const int il = is * 16 + il0;
    float4 p0 = *(float4*)&p_s[bl * 516 + il * 8];
    float4 p1 = *(float4*)&p_s[bl * 516 + il * 8 + 4];
    float acc = 0.f;
#pragma unroll
    for (int dd = 0; dd < 16; ++dd) {
      float4 r0 = *(float4*)&rw_s[dd * 516 + il * 8];
      float4 r1 = *(float4*)&rw_s[dd * 516 + il * 8 + 4];
      float h = r0.x * p0.x + r0.y * p0.y + r0.z * p0.z + r0.w * p0.w +
                r1.x * p1.x + r1.y * p1.y + r1.z * p1.z + r1.w * p1.w;
      acc += h * ocv[dd];
    }
    size_t gi = (size_t)((b0 + bl) * 10 + o) * 1152 + i0 + il;
    blog[gi] = accum ? (blog[gi] + acc) : acc;
  }
}

__global__ __launch_bounds__(256) void k_softmax(const float* __restrict__ blog, float* __restrict__ cbuf) {
  const int b = blockIdx.x;
  const int i = blockIdx.y * 256 + threadIdx.x;
  if (i >= 1152) return;
  float v[10];
  float m = -1e30f;
#pragma unroll
  for (int o = 0; o < 10; ++o) {
    v[o] = blog[(size_t)(b * 10 + o) * 1152 + i];
    m = fmaxf(m, v[o]);
  }
  float s = 0.f;
#pragma unroll
  for (int o = 0; o < 10; ++o) {
    v[o] = __expf(v[o] - m);
    s += v[o];
  }
  float inv = 1.f / s;
#pragma unroll
  for (int o = 0; o < 10; ++o) cbuf[(size_t)(b * 10 + o) * 1152 + i] = v[o] * inv;
}

__global__ __launch_bounds__(256) void k_argmax(const float* __restrict__ len_, const float* __restrict__ outc,
                                                int* __restrict__ win, float* __restrict__ oc16) {
  const int b = blockIdx.x * 256 + threadIdx.x;
  if (b >= 512) return;
  float best = len_[b * 10];
  int wi = 0;
  for (int o = 1; o < 10; ++o) {
    float v = len_[b * 10 + o];
    if (v > best) { best = v; wi = o; }
  }
  win[b] = wi;
  for (int k = 0; k < 16; ++k) oc16[b * 16 + k] = outc[(size_t)b * 160 + wi * 16 + k];
}

__global__ __launch_bounds__(256) void k_dec1(const float* __restrict__ oc16, const int* __restrict__ win,
                                              const float* __restrict__ w, const float* __restrict__ bias,
                                              float* __restrict__ d1) {
  const int b = blockIdx.x, t = threadIdx.x;
  const int wi = win[b];
  float ocv[16];
#pragma unroll
  for (int k = 0; k < 16; ++k) ocv[k] = oc16[b * 16 + k];
#pragma unroll
  for (int rep = 0; rep < 2; ++rep) {
    int j = t + rep * 256;
    const float* wr = w + (size_t)j * 160 + wi * 16;
    float acc = bias[j];
#pragma unroll
    for (int k = 0; k < 16; ++k) acc += ocv[k] * wr[k];
    d1[(size_t)b * 512 + j] = fmaxf(acc, 0.f);
  }
}

template <int K, int ACT>
__global__ __launch_bounds__(256) void k_fc(const float* __restrict__ in, const float* __restrict__ w,
                                            const float* __restrict__ bias, float* __restrict__ out, int M) {
  __shared__ __align__(16) float w_s[16 * 64];
  __shared__ __align__(16) float i_s[16 * 64];
  const int t = threadIdx.x;
  const int j0 = blockIdx.x * 64, b0 = blockIdx.y * 64;
  const int tx = t & 15, ty = t >> 4;
  const int jl = tx * 4, bl = ty * 4;
  float acc[4][4];
#pragma unroll
  for (int i = 0; i < 4; ++i)
#pragma unroll
    for (int j = 0; j < 4; ++j) acc[i][j] = 0.f;
  const int rr = t >> 2, kq = (t & 3) * 4;
  for (int k0 = 0; k0 < K; k0 += 16) {
    __syncthreads();
    float4 wv = make_float4(0.f, 0.f, 0.f, 0.f);
    if (j0 + rr < M) wv = *(const float4*)&w[(size_t)(j0 + rr) * K + k0 + kq];
    float4 iv = *(const float4*)&in[(size_t)(b0 + rr) * K + k0 + kq];
    w_s[(kq + 0) * 64 + rr] = wv.x;
    w_s[(kq + 1) * 64 + rr] = wv.y;
    w_s[(kq + 2) * 64 + rr] = wv.z;
    w_s[(kq + 3) * 64 + rr] = wv.w;
    i_s[(kq + 0) * 64 + rr] = iv.x;
    i_s[(kq + 1) * 64 + rr] = iv.y;
    i_s[(kq + 2) * 64 + rr] = iv.z;
    i_s[(kq + 3) * 64 + rr] = iv.w;
    __syncthreads();
#pragma unroll
    for (int k = 0; k < 16; ++k) {
      float4 a = *(float4*)&w_s[k * 64 + jl];
      float4 v = *(float4*)&i_s[k * 64 + bl];
      float av[4] = {a.x, a.y, a.z, a.w};
      float vv[4] = {v.x, v.y, v.z, v.w};
#pragma unroll
      for (int jj = 0; jj < 4; ++jj)
#pragma unroll
        for (int bb = 0; bb < 4; ++bb) acc[jj][bb] += av[jj] * vv[bb];
    }
  }
#pragma unroll
  for (int jj = 0; jj < 4; ++jj) {
    int j = j0 + jl + jj;
    if (j >= M) continue;
    float bs = bias[j];
#pragma unroll
    for (int bb = 0; bb < 4; ++bb) {
      float v = acc[jj][bb] + bs;
      if (ACT == 0) {
        v = fmaxf(v, 0.f);
      } else {
        v = 1.f / (1.f + __expf(-v));
        v = fminf(fmaxf(v, 0.f), 1.f);
      }
      out[(size_t)(b0 + bl + bb) * M + j] = v;
    }
  }
}

extern "C" void kernel_launch(void* const* d_in, const int* in_sizes, int n_in,
                              void* d_out, int out_size, void* d_ws, size_t ws_size,
                              hipStream_t stream) {
  (void)in_sizes; (void)n_in; (void)out_size; (void)ws_size;
  const float* x   = (const float*)d_in[0];
  const float* w1  = (const float*)d_in[1];
  const float* b1  = (const float*)d_in[2];
  const float* w2  = (const float*)d_in[3];
  const float* b2  = (const float*)d_in[4];
  const float* rw  = (const float*)d_in[5];
  const float* d1w = (const float*)d_in[6];
  const float* d1b = (const float*)d_in[7];
  const float* d2w = (const float*)d_in[8];
  const float* d2b = (const float*)d_in[9];
  const float* d3w = (const float*)d_in[10];
  const float* d3b = (const float*)d_in[11];
  float* out = (float*)d_out;

  char* wsb = (char*)d_ws;
  size_t cur = 0;
  auto alloc = [&](size_t bytes) -> char* {
    char* p = wsb + cur;
    cur += (bytes + 255) & ~(size_t)255;
    return p;
  };
  unsigned short* W2P = (unsigned short*)alloc(21233664);  // 648 x 32KB tiles
  float* PART = (float*)alloc(75497472);                   // 4 x 18432 x 256 f32
  float* PRI  = (float*)alloc(18874368);                   // 18432 x 256
  float* OUTC = (float*)alloc(327680);                     // 512 x 160
  float* OC   = (float*)alloc(32768);
  int*   WIN  = (int*)alloc(2048);
  float* D1   = (float*)alloc(1048576);
  float* D2   = (float*)alloc(2097152);
  unsigned short* H1H = (unsigned short*)alloc(52428800);  // 256b x 400 x 256
  unsigned short* H1L = (unsigned short*)alloc(52428800);
  // routing-phase overlays in the dead H1 region (53.1 MB < 104.9 MB):
  float* C  = (float*)H1H;                                 // 23.6 MB
  float* BL = (float*)((char*)H1H + 23592960);             // 23.6 MB
  // RWPA (5.9 MB) overlays PART (dead after k_redsquash):
  unsigned short* RWPA = (unsigned short*)PART;

  k_w2p<<<256, 256, 0, stream>>>(w2, W2P);
  for (int b0 = 0; b0 < 512; b0 += 256) {
    k_conv1<<<dim3(256, 4), 256, 0, stream>>>(x, w1, b1, H1H, H1L, b0);
    k_conv2m<<<dim3(144, 1, 4), 256, 0, stream>>>(H1H, H1L, W2P, PART, b0);
  }
  k_redsquash<<<2304, 256, 0, stream>>>(PART, b2, PRI);
  k_rwp<<<180, 256, 0, stream>>>(rw, RWPA);

  dim3 gA(32, 10);
  dim3 gB(32, 18, 10);
  k_passAf<<<gA, 256, 0, stream>>>(RWPA, PRI, C, OUTC, out, 0, 0);
  k_passB<<<gB, 256, 0, stream>>>(rw, PRI, OUTC, BL, 0);
  k_softmax<<<dim3(512, 5), 256, 0, stream>>>(BL, C);
  k_passAf<<<gA, 256, 0, stream>>>(RWPA, PRI, C, OUTC, out, 1, 0);
  k_passB<<<gB, 256, 0, stream>>>(rw, PRI, OUTC, BL, 1);
  k_softmax<<<dim3(512, 5), 256, 0, stream>>>(BL, C);
  k_passAf<<<gA, 256, 0, stream>>>(RWPA, PRI, C, OUTC, out, 2, 1);

  k_argmax<<<2, 256, 0, stream>>>(out, OUTC, WIN, OC);
  k_dec1<<<512, 256, 0, stream>>>(OC, WIN, d1w, d1b, D1);
  k_fc<512, 0><<<dim3(16, 8), 256, 0, stream>>>(D1, d2w, d2b, D2, 1024);
  k_fc<1024, 1><<<dim3(13, 8), 256, 0, stream>>>(D2, d3w, d3b, out + 5120, 784);
}

// Round 10
// 1332.776 us; speedup vs baseline: 1.8145x; 1.1507x over previous
//
#include <hip/hip_runtime.h>

typedef short short8 __attribute__((ext_vector_type(8)));
typedef float floatx4 __attribute__((ext_vector_type(4)));

__device__ __forceinline__ unsigned short bf16rn(float x) {
  union { float f; unsigned int u; } v; v.f = x;
  unsigned int r = v.u + 0x7fffu + ((v.u >> 16) & 1u);
  return (unsigned short)(r >> 16);
}
__device__ __forceinline__ float bf16f(unsigned short h) {
  union { unsigned int u; float f; } v; v.u = ((unsigned int)h) << 16;
  return v.f;
}
__device__ __forceinline__ void gload16(const void* g, void* l) {
  __builtin_amdgcn_global_load_lds((const __attribute__((address_space(1))) unsigned int*)g,
                                   (__attribute__((address_space(3))) unsigned int*)l, 16, 0, 0);
}
__device__ __forceinline__ unsigned swz128(int row) {
  return ((row & 1) << 6) | ((row & 2) << 4) | ((row & 4) << 2);
}
__device__ __forceinline__ unsigned s4of(int row) {
  return ((row & 1) << 2) | (row & 2) | ((row & 4) >> 2);
}

// ---------------------------------------------------------------------------
// W2 pack: per (kk, cb) a 32KB tile = exact LDS A-image (conv2m format).
// ---------------------------------------------------------------------------
__global__ __launch_bounds__(256) void k_w2p(const float* __restrict__ w2,
                                             unsigned short* __restrict__ w2p) {
  __shared__ float sm[20736];
  const int t = threadIdx.x;
  const int co = blockIdx.x;  // 0..255
  for (int q = t; q < 20736; q += 256) sm[q] = w2[(size_t)co * 20736 + q];
  __syncthreads();
  const unsigned s4 = s4of(co);
  unsigned short* base = w2p + (size_t)co * 64;
  for (int q = t; q < 5184; q += 256) {  // 81 kk x 8 cb x 8 chunks
    int kk = q >> 6, r = q & 63, cb = r >> 3, cp = r & 7;
    unsigned src = (unsigned)cp ^ s4;
    int half = src >> 2, oct = src & 3;
    const float* col = &sm[(cb * 32 + oct * 8) * 81 + kk];
    union { unsigned short u[8]; uint4 v; } pk;
#pragma unroll
    for (int j = 0; j < 8; ++j) {
      float v = col[j * 81];
      unsigned short hi = bf16rn(v);
      pk.u[j] = half ? bf16rn(v - bf16f(hi)) : hi;
    }
    *(uint4*)(base + (size_t)(kk * 8 + cb) * 16384 + cp * 8) = pk.v;
  }
}

// ---------------------------------------------------------------------------
// conv1: NHWC split-bf16 out; grid (bc, 4 co-quarters)
// ---------------------------------------------------------------------------
__global__ __launch_bounds__(256) void k_conv1(const float* __restrict__ x, const float* __restrict__ w1,
                                               const float* __restrict__ b1,
                                               unsigned short* __restrict__ h1h,
                                               unsigned short* __restrict__ h1l, int b0) {
  __shared__ float xs[784];
  __shared__ float wsm[64 * 81];
  const int t = threadIdx.x;
  const int b = b0 + blockIdx.x;
  const int coq = blockIdx.y;
  for (int q = t; q < 784; q += 256) xs[q] = x[(size_t)b * 784 + q];
  for (int q = t; q < 5184; q += 256) wsm[q] = w1[coq * 5184 + q];
  __syncthreads();
  const int col = t & 63, yg = t >> 6;
  const int co = coq * 64 + col;
  const float bv = b1[co];
  unsigned short* oh = h1h + (size_t)blockIdx.x * 102400 + co;
  unsigned short* ol = h1l + (size_t)blockIdx.x * 102400 + co;
  for (int yy = 0; yy < 5; ++yy) {
    const int y = yg * 5 + yy;
    float acc[20];
#pragma unroll
    for (int i = 0; i < 20; ++i) acc[i] = bv;
    for (int ky = 0; ky < 9; ++ky) {
      float row[28];
#pragma unroll
      for (int cc = 0; cc < 28; ++cc) row[cc] = xs[(y + ky) * 28 + cc];
#pragma unroll
      for (int kx = 0; kx < 9; ++kx) {
        float wv = wsm[col * 81 + ky * 9 + kx];
#pragma unroll
        for (int xx = 0; xx < 20; ++xx) acc[xx] += row[xx + kx] * wv;
      }
    }
#pragma unroll
    for (int xx = 0; xx < 20; ++xx) {
      unsigned short hi = bf16rn(acc[xx]);
      unsigned short lo = bf16rn(acc[xx] - bf16f(hi));
      size_t p = (size_t)(y * 20 + xx) * 256;
      oh[p] = hi; ol[p] = lo;
    }
  }
}

// ---------------------------------------------------------------------------
// conv2 GEMM: r0/r6 proven (353us/dispatch). BM=256 x BN=64, BK=32, z=4.
// ---------------------------------------------------------------------------
__global__ __launch_bounds__(256) void k_conv2m(const unsigned short* __restrict__ h1h,
                                                const unsigned short* __restrict__ h1l,
                                                const unsigned short* __restrict__ w2p,
                                                float* __restrict__ part, int b0) {
  __shared__ __align__(16) char smem[40960];
  const int t = threadIdx.x;
  const int lin = blockIdx.x + 144 * blockIdx.z;   // 0..575
  const int xcd = lin & 7, idx = lin >> 3;         // idx 0..71
  const int zz = xcd & 3;                          // kk-range, XCD pair {zz, zz+4}
  const int n0 = ((xcd >> 2) * 72 + idx) * 64;     // n-block
  const int kk0 = (zz == 0) ? 0 : (21 + 20 * (zz - 1));
  const int kkn = (zz == 0) ? 21 : 20;

  const int wid = t >> 6, lane = t & 63;
  const int l15 = lane & 15, l4 = lane >> 4;
  const int brow = t >> 2, bc4 = t & 3;
  size_t bsrc;
  {
    int nloc = n0 + brow;
    int bi = nloc / 36, pp = nloc - bi * 36;
    int oy = pp / 6, ox = pp - oy * 6;
    bsrc = ((size_t)((bi * 20 + 2 * oy) * 20 + 2 * ox)) * 256;
  }
  const unsigned bswz = swz128(brow);
  const unsigned bo_hi = (unsigned)(brow * 128) + (((unsigned)(bc4 * 16)) ^ bswz);
  const unsigned bo_lo = (unsigned)(brow * 128) + (((unsigned)(64 + bc4 * 16)) ^ bswz);

  floatx4 acc[4][4];
#pragma unroll
  for (int i = 0; i < 4; ++i)
#pragma unroll
    for (int j = 0; j < 4; ++j) acc[i][j] = (floatx4)0.f;

  for (int kq = 0; kq < kkn; ++kq) {
    const int kk = kk0 + kq;
    const int ky = kk / 9, kx = kk - ky * 9;
    const int koff = (ky * 20 + kx) * 256;
    for (int cb = 0; cb < 8; ++cb) {
      const unsigned short* abase = w2p + (size_t)(kk * 8 + cb) * 16384;
#pragma unroll
      for (int j = 0; j < 8; ++j) {
        const int seg = j * 4 + wid;
        gload16(abase + seg * 512 + lane * 8, smem + seg * 1024);
      }
      {
        const unsigned short* sh = h1h + bsrc + koff + cb * 32 + bc4 * 8;
        const unsigned short* sl = h1l + bsrc + koff + cb * 32 + bc4 * 8;
        uint4 vh = *(const uint4*)sh;
        uint4 vl = *(const uint4*)sl;
        *(uint4*)(smem + 32768 + bo_hi) = vh;
        *(uint4*)(smem + 32768 + bo_lo) = vl;
      }
      __syncthreads();
      short8 bh[4], blo[4];
#pragma unroll
      for (int nf = 0; nf < 4; ++nf) {
        const int br = nf * 16 + l15;
        const unsigned s = swz128(br);
        bh[nf] = *(const short8*)(smem + 32768 + br * 128 + (((unsigned)(l4 * 16)) ^ s));
        blo[nf] = *(const short8*)(smem + 32768 + br * 128 + (((unsigned)(64 + l4 * 16)) ^ s));
      }
#pragma unroll
      for (int mf = 0; mf < 4; ++mf) {
        const int ar = wid * 64 + mf * 16 + l15;
        const unsigned s = swz128(ar);
        short8 ah = *(const short8*)(smem + ar * 128 + (((unsigned)(l4 * 16)) ^ s));
        short8 al = *(const short8*)(smem + ar * 128 + (((unsigned)(64 + l4 * 16)) ^ s));
#pragma unroll
        for (int nf = 0; nf < 4; ++nf) {
          acc[mf][nf] = __builtin_amdgcn_mfma_f32_16x16x32_bf16(ah, bh[nf], acc[mf][nf], 0, 0, 0);
          acc[mf][nf] = __builtin_amdgcn_mfma_f32_16x16x32_bf16(ah, blo[nf], acc[mf][nf], 0, 0, 0);
          acc[mf][nf] = __builtin_amdgcn_mfma_f32_16x16x32_bf16(al, bh[nf], acc[mf][nf], 0, 0, 0);
        }
      }
      __syncthreads();
    }
  }
  float* po = part + (size_t)zz * 4718592;
#pragma unroll
  for (int mf = 0; mf < 4; ++mf) {
#pragma unroll
    for (int nf = 0; nf < 4; ++nf) {
      int cog = wid * 64 + mf * 16 + l4 * 4;
      int ng = b0 * 36 + n0 + nf * 16 + l15;
      *(floatx4*)&po[(size_t)ng * 256 + cog] = acc[mf][nf];
    }
  }
}

// reduce 4 K-split partials + bias, squash -> PRI
__global__ __launch_bounds__(256) void k_redsquash(const float* __restrict__ part,
                                                   const float* __restrict__ b2,
                                                   float* __restrict__ pri) {
  const int idx = blockIdx.x * 256 + threadIdx.x;  // < 589824
  const int n = idx >> 5, cap = idx & 31;
  const size_t o = (size_t)n * 256 + cap * 8;
  float s[8];
#pragma unroll
  for (int j = 0; j < 8; ++j) s[j] = b2[cap * 8 + j];
#pragma unroll
  for (int z = 0; z < 4; ++z) {
    const float4 a0 = *(const float4*)&part[(size_t)z * 4718592 + o];
    const float4 a1 = *(const float4*)&part[(size_t)z * 4718592 + o + 4];
    s[0] += a0.x; s[1] += a0.y; s[2] += a0.z; s[3] += a0.w;
    s[4] += a1.x; s[5] += a1.y; s[6] += a1.z; s[7] += a1.w;
  }
  float ss = 0.f;
#pragma unroll
  for (int j = 0; j < 8; ++j) ss += s[j] * s[j];
  float nn = sqrtf(ss);
  float sc = ss / (1.f + ss) / (nn + 1e-8f);
  float4 o0, o1;
  o0.x = s[0] * sc; o0.y = s[1] * sc; o0.z = s[2] * sc; o0.w = s[3] * sc;
  o1.x = s[4] * sc; o1.y = s[5] * sc; o1.z = s[6] * sc; o1.w = s[7] * sc;
  *(float4*)&pri[o] = o0;
  *(float4*)&pri[o + 4] = o1;
}

// ---------------------------------------------------------------------------
// passA (r6 proven). rw_s [d(16)][il*8+k] pad 516; p_s [bl(16)][off].
// float4-vectorized staging; compute identical to proven scalar version.
// ---------------------------------------------------------------------------
__global__ __launch_bounds__(256, 2) void k_passA(const float* __restrict__ rw, const float* __restrict__ pri,
                                                  const float* __restrict__ cbuf, float* __restrict__ spart,
                                                  int iter) {
  __shared__ __align__(16) float rw_s[16 * 516];
  __shared__ __align__(16) float p_s[16 * 516];
  __shared__ __align__(16) float c_s[1024];
  const int t = threadIdx.x;
  const int b0 = blockIdx.x * 16, i0 = blockIdx.y * 64, o = blockIdx.z;
  const float* rsrc = rw + (size_t)o * 147456 + (size_t)i0 * 128;
  for (int m = t; m < 2048; m += 256) {
    int il = m >> 5, r = m & 31, d = r >> 1, kh = (m & 1) * 4;
    float4 v = *(const float4*)&rsrc[il * 128 + d * 8 + kh];
    *(float4*)&rw_s[d * 516 + il * 8 + kh] = v;
  }
  for (int m = t; m < 2048; m += 256) {
    int bl = m >> 7, off = (m & 127) * 4;
    float4 v = *(const float4*)&pri[(size_t)(b0 + bl) * 9216 + i0 * 8 + off];
    *(float4*)&p_s[bl * 516 + off] = v;
  }
  if (iter > 0) {
    for (int m = t; m < 256; m += 256) {
      int bl = m >> 4, il4 = (m & 15) * 4;
      float4 v = *(const float4*)&cbuf[(size_t)((b0 + bl) * 10 + o) * 1152 + i0 + il4];
      *(float4*)&c_s[bl * 64 + il4] = v;
    }
  }
  __syncthreads();
  const int d = t & 15, bl = t >> 4;
  float acc = 0.f;
  for (int il = 0; il < 64; ++il) {
    float cv = (iter == 0) ? 0.1f : c_s[bl * 64 + il];
    float4 p0 = *(float4*)&p_s[bl * 516 + il * 8];
    float4 p1 = *(float4*)&p_s[bl * 516 + il * 8 + 4];
    float4 r0 = *(float4*)&rw_s[d * 516 + il * 8];
    float4 r1 = *(float4*)&rw_s[d * 516 + il * 8 + 4];
    float dt = r0.x * p0.x + r0.y * p0.y + r0.z * p0.z + r0.w * p0.w +
               r1.x * p1.x + r1.y * p1.y + r1.z * p1.z + r1.w * p1.w;
    acc += cv * dt;
  }
  spart[((size_t)blockIdx.y * 512 + (b0 + bl)) * 160 + o * 16 + d] = acc;
}

__global__ __launch_bounds__(256) void k_reduce(const float* __restrict__ spart, float* __restrict__ outc,
                                                float* __restrict__ len_out, int final_) {
  const int t = threadIdx.x;
  const int b = blockIdx.x;
  if (t >= 160) return;
  const int o = t / 16, d = t & 15;
  float s = 0.f;
  for (int ic = 0; ic < 18; ++ic) s += spart[((size_t)ic * 512 + b) * 160 + t];
  float ss = s * s;
  ss += __shfl_xor(ss, 1, 16);
  ss += __shfl_xor(ss, 2, 16);
  ss += __shfl_xor(ss, 4, 16);
  ss += __shfl_xor(ss, 8, 16);
  float n = sqrtf(ss);
  float sc = ss / (1.f + ss) / (n + 1e-8f);
  outc[(size_t)b * 160 + t] = sc * s;
  if (final_ && d == 0) len_out[b * 10 + o] = sc * n;
}

// ---------------------------------------------------------------------------
// passB micro-opt (this round's single change): p_s LDS buffer removed.
// p has NO cross-thread reuse (unlike rw, read 16x) -- each thread preloads
// its 8 float4 of PRI to REGISTERS, issued BEFORE rw staging so global
// latency drains under the staging + barrier. Deletes 8 ds_write + 8
// ds_read/thread; LDS 67->34KB => occupancy 2->4 blocks/CU. Values and
// accumulation order bit-identical to r6.
// ---------------------------------------------------------------------------
__global__ __launch_bounds__(256, 4) void k_passB(const float* __restrict__ rw, const float* __restrict__ pri,
                                                  const float* __restrict__ outc, float* __restrict__ blog,
                                                  int accum) {
  __shared__ __align__(16) float rw_s[16 * 516];
  __shared__ float oc_s[256];
  const int t = threadIdx.x;
  const int b0 = blockIdx.x * 16, i0 = blockIdx.y * 64, o = blockIdx.z;
  const int il0 = t & 15, bl = t >> 4;
  // p direct-to-reg: issue first (coalesced 512B runs per 16-lane group)
  float4 pr0[4], pr1[4];
#pragma unroll
  for (int is = 0; is < 4; ++is) {
    const float* ps = &pri[(size_t)(b0 + bl) * 9216 + i0 * 8 + (size_t)(is * 16 + il0) * 8];
    pr0[is] = *(const float4*)ps;
    pr1[is] = *(const float4*)(ps + 4);
  }
  const float* rsrc = rw + (size_t)o * 147456 + (size_t)i0 * 128;
  for (int m = t; m < 2048; m += 256) {
    int il = m >> 5, r = m & 31, d = r >> 1, kh = (m & 1) * 4;
    float4 v = *(const float4*)&rsrc[il * 128 + d * 8 + kh];
    *(float4*)&rw_s[d * 516 + il * 8 + kh] = v;
  }
  oc_s[t] = outc[(size_t)(b0 + (t >> 4)) * 160 + o * 16 + (t & 15)];
  __syncthreads();
  float ocv[16];
#pragma unroll
  for (int k = 0; k < 16; ++k) ocv[k] = oc_s[bl * 16 + k];
#pragma unroll
  for (int is = 0; is < 4; ++is) {
    const int il = is * 16 + il0;
    float4 p0 = pr0[is];
    float4 p1 = pr1[is];
    float acc = 0.f;
#pragma unroll
    for (int dd = 0; dd < 16; ++dd) {
      float4 r0 = *(float4*)&rw_s[dd * 516 + il * 8];
      float4 r1 = *(float4*)&rw_s[dd * 516 + il * 8 + 4];
      float h = r0.x * p0.x + r0.y * p0.y + r0.z * p0.z + r0.w * p0.w +
                r1.x * p1.x + r1.y * p1.y + r1.z * p1.z + r1.w * p1.w;
      acc += h * ocv[dd];
    }
    size_t gi = (size_t)((b0 + bl) * 10 + o) * 1152 + i0 + il;
    blog[gi] = accum ? (blog[gi] + acc) : acc;
  }
}

__global__ __launch_bounds__(256) void k_softmax(const float* __restrict__ blog, float* __restrict__ cbuf) {
  const int b = blockIdx.x;
  const int i = blockIdx.y * 256 + threadIdx.x;
  if (i >= 1152) return;
  float v[10];
  float m = -1e30f;
#pragma unroll
  for (int o = 0; o < 10; ++o) {
    v[o] = blog[(size_t)(b * 10 + o) * 1152 + i];
    m = fmaxf(m, v[o]);
  }
  float s = 0.f;
#pragma unroll
  for (int o = 0; o < 10; ++o) {
    v[o] = __expf(v[o] - m);
    s += v[o];
  }
  float inv = 1.f / s;
#pragma unroll
  for (int o = 0; o < 10; ++o) cbuf[(size_t)(b * 10 + o) * 1152 + i] = v[o] * inv;
}

__global__ __launch_bounds__(256) void k_argmax(const float* __restrict__ len_, const float* __restrict__ outc,
                                                int* __restrict__ win, float* __restrict__ oc16) {
  const int b = blockIdx.x * 256 + threadIdx.x;
  if (b >= 512) return;
  float best = len_[b * 10];
  int wi = 0;
  for (int o = 1; o < 10; ++o) {
    float v = len_[b * 10 + o];
    if (v > best) { best = v; wi = o; }
  }
  win[b] = wi;
  for (int k = 0; k < 16; ++k) oc16[b * 16 + k] = outc[(size_t)b * 160 + wi * 16 + k];
}

__global__ __launch_bounds__(256) void k_dec1(const float* __restrict__ oc16, const int* __restrict__ win,
                                              const float* __restrict__ w, const float* __restrict__ bias,
                                              float* __restrict__ d1) {
  const int b = blockIdx.x, t = threadIdx.x;
  const int wi = win[b];
  float ocv[16];
#pragma unroll
  for (int k = 0; k < 16; ++k) ocv[k] = oc16[b * 16 + k];
#pragma unroll
  for (int rep = 0; rep < 2; ++rep) {
    int j = t + rep * 256;
    const float* wr = w + (size_t)j * 160 + wi * 16;
    float acc = bias[j];
#pragma unroll
    for (int k = 0; k < 16; ++k) acc += ocv[k] * wr[k];
    d1[(size_t)b * 512 + j] = fmaxf(acc, 0.f);
  }
}

template <int K, int ACT>
__global__ __launch_bounds__(256) void k_fc(const float* __restrict__ in, const float* __restrict__ w,
                                            const float* __restrict__ bias, float* __restrict__ out, int M) {
  __shared__ __align__(16) float w_s[16 * 64];
  __shared__ __align__(16) float i_s[16 * 64];
  const int t = threadIdx.x;
  const int j0 = blockIdx.x * 64, b0 = blockIdx.y * 64;
  const int tx = t & 15, ty = t >> 4;
  const int jl = tx * 4, bl = ty * 4;
  float acc[4][4];
#pragma unroll
  for (int i = 0; i < 4; ++i)
#pragma unroll
    for (int j = 0; j < 4; ++j) acc[i][j] = 0.f;
  const int rr = t >> 2, kq = (t & 3) * 4;
  for (int k0 = 0; k0 < K; k0 += 16) {
    __syncthreads();
    float4 wv = make_float4(0.f, 0.f, 0.f, 0.f);
    if (j0 + rr < M) wv = *(const float4*)&w[(size_t)(j0 + rr) * K + k0 + kq];
    float4 iv = *(const float4*)&in[(size_t)(b0 + rr) * K + k0 + kq];
    w_s[(kq + 0) * 64 + rr] = wv.x;
    w_s[(kq + 1) * 64 + rr] = wv.y;
    w_s[(kq + 2) * 64 + rr] = wv.z;
    w_s[(kq + 3) * 64 + rr] = wv.w;
    i_s[(kq + 0) * 64 + rr] = iv.x;
    i_s[(kq + 1) * 64 + rr] = iv.y;
    i_s[(kq + 2) * 64 + rr] = iv.z;
    i_s[(kq + 3) * 64 + rr] = iv.w;
    __syncthreads();
#pragma unroll
    for (int k = 0; k < 16; ++k) {
      float4 a = *(float4*)&w_s[k * 64 + jl];
      float4 v = *(float4*)&i_s[k * 64 + bl];
      float av[4] = {a.x, a.y, a.z, a.w};
      float vv[4] = {v.x, v.y, v.z, v.w};
#pragma unroll
      for (int jj = 0; jj < 4; ++jj)
#pragma unroll
        for (int bb = 0; bb < 4; ++bb) acc[jj][bb] += av[jj] * vv[bb];
    }
  }
#pragma unroll
  for (int jj = 0; jj < 4; ++jj) {
    int j = j0 + jl + jj;
    if (j >= M) continue;
    float bs = bias[j];
#pragma unroll
    for (int bb = 0; bb < 4; ++bb) {
      float v = acc[jj][bb] + bs;
      if (ACT == 0) {
        v = fmaxf(v, 0.f);
      } else {
        v = 1.f / (1.f + __expf(-v));
        v = fminf(fmaxf(v, 0.f), 1.f);
      }
      out[(size_t)(b0 + bl + bb) * M + j] = v;
    }
  }
}

extern "C" void kernel_launch(void* const* d_in, const int* in_sizes, int n_in,
                              void* d_out, int out_size, void* d_ws, size_t ws_size,
                              hipStream_t stream) {
  (void)in_sizes; (void)n_in; (void)out_size; (void)ws_size;
  const float* x   = (const float*)d_in[0];
  const float* w1  = (const float*)d_in[1];
  const float* b1  = (const float*)d_in[2];
  const float* w2  = (const float*)d_in[3];
  const float* b2  = (const float*)d_in[4];
  const float* rw  = (const float*)d_in[5];
  const float* d1w = (const float*)d_in[6];
  const float* d1b = (const float*)d_in[7];
  const float* d2w = (const float*)d_in[8];
  const float* d2b = (const float*)d_in[9];
  const float* d3w = (const float*)d_in[10];
  const float* d3b = (const float*)d_in[11];
  float* out = (float*)d_out;

  char* wsb = (char*)d_ws;
  size_t cur = 0;
  auto alloc = [&](size_t bytes) -> char* {
    char* p = wsb + cur;
    cur += (bytes + 255) & ~(size_t)255;
    return p;
  };
  unsigned short* W2P = (unsigned short*)alloc(21233664);  // 648 x 32KB tiles
  float* PART = (float*)alloc(75497472);                   // 4 x 18432 x 256 f32
  float* PRI  = (float*)alloc(18874368);                   // 18432 x 256
  float* OUTC = (float*)alloc(327680);                     // 512 x 160
  float* OC   = (float*)alloc(32768);
  int*   WIN  = (int*)alloc(2048);
  float* D1   = (float*)alloc(1048576);
  float* D2   = (float*)alloc(2097152);
  unsigned short* H1H = (unsigned short*)alloc(52428800);  // 256b x 400 x 256
  unsigned short* H1L = (unsigned short*)alloc(52428800);
  // routing-phase overlays in the dead H1 region (53.1 MB < 104.9 MB):
  float* C  = (float*)H1H;                                 // 23.6 MB
  float* BL = (float*)((char*)H1H + 23592960);             // 23.6 MB
  float* SP = (float*)((char*)H1H + 47185920);             // 5.9 MB

  k_w2p<<<256, 256, 0, stream>>>(w2, W2P);
  for (int b0 = 0; b0 < 512; b0 += 256) {
    k_conv1<<<dim3(256, 4), 256, 0, stream>>>(x, w1, b1, H1H, H1L, b0);
    k_conv2m<<<dim3(144, 1, 4), 256, 0, stream>>>(H1H, H1L, W2P, PART, b0);
  }
  k_redsquash<<<2304, 256, 0, stream>>>(PART, b2, PRI);

  dim3 gAB(32, 18, 10);
  k_passA<<<gAB, 256, 0, stream>>>(rw, PRI, C, SP, 0);
  k_reduce<<<512, 256, 0, stream>>>(SP, OUTC, out, 0);
  k_passB<<<gAB, 256, 0, stream>>>(rw, PRI, OUTC, BL, 0);
  k_softmax<<<dim3(512, 5), 256, 0, stream>>>(BL, C);
  k_passA<<<gAB, 256, 0, stream>>>(rw, PRI, C, SP, 1);
  k_reduce<<<512, 256, 0, stream>>>(SP, OUTC, out, 0);
  k_passB<<<gAB, 256, 0, stream>>>(rw, PRI, OUTC, BL, 1);
  k_softmax<<<dim3(512, 5), 256, 0, stream>>>(BL, C);
  k_passA<<<gAB, 256, 0, stream>>>(rw, PRI, C, SP, 2);
  k_reduce<<<512, 256, 0, stream>>>(SP, OUTC, out, 1);

  k_argmax<<<2, 256, 0, stream>>>(out, OUTC, WIN, OC);
  k_dec1<<<512, 256, 0, stream>>>(OC, WIN, d1w, d1b, D1);
  k_fc<512, 0><<<dim3(16, 8), 256, 0, stream>>>(D1, d2w, d2b, D2, 1024);
  k_fc<1024, 1><<<dim3(13, 8), 256, 0, stream>>>(D2, d3w, d3b, out + 5120, 784);
}